// Round 1
// 534.626 us; speedup vs baseline: 1.0039x; 1.0039x over previous
//
#include <hip/hip_runtime.h>
#include <math.h>

#define N    257     // state dim
#define AP   258     // doubles per A row (cols 0..256 = S, col 257 = rhs)
#define MM   128     // rotation pairs
#define LL   512     // seq length
#define BB   4       // batch
#define NB   32      // panel width

// ws byte layout:
#define A_BYTE    0         // double[257*258] = 530448
#define W0_BYTE   530448    // float[257]  -> ends 531476
#define CXY_BYTE  531488    // float[4096] -> ends 547872
#define PW_BYTE   547904    // double[32*257] = 65792 -> ends 613696
#define U12_BYTE  613696    // double[32*226] = 57856 -> ends 671552
// total ~672 KB (ws >= 1.31 MB proven by rounds 1-5)

// ---------------------------------------------------------------------------
// prefix sums of x[b,:,comp]: theta[b,l,m] = cx[b,l]*om0[m] + cy[b,l]*om1[m]
// ---------------------------------------------------------------------------
__global__ __launch_bounds__(512) void scan_kernel(const float* __restrict__ x,
                                                   void* __restrict__ wsv) {
  const int tid  = threadIdx.x;
  const int wave = tid >> 6, lane = tid & 63;
  const int b    = wave >> 1, comp = wave & 1;

  const float* xp = x + ((size_t)b * LL) * 2 + comp;
  double loc[8];
  double run = 0.0;
  #pragma unroll
  for (int e = 0; e < 8; ++e) {
    run += (double)xp[(lane * 8 + e) * 2];
    loc[e] = run;
  }
  double tot = run;
  #pragma unroll
  for (int off = 1; off < 64; off <<= 1) {
    const double o = __shfl_up(tot, off);
    if (lane >= off) tot += o;
  }
  const double excl = tot - run;
  float* cp = (float*)((char*)wsv + CXY_BYTE) + ((size_t)b * LL) * 2 + comp;
  #pragma unroll
  for (int e = 0; e < 8; ++e)
    cp[(lane * 8 + e) * 2] = (float)(excl + loc[e]);
}

// ---------------------------------------------------------------------------
// stage A = [S | z0] in fp64, grid-wide
// ---------------------------------------------------------------------------
__global__ __launch_bounds__(256) void stage_kernel(const float* __restrict__ S,
                                                    const float* __restrict__ z0,
                                                    void* __restrict__ wsv) {
  double* A = (double*)((char*)wsv + A_BYTE);
  const int idx = blockIdx.x * 256 + threadIdx.x;
  if (idx < N * N) {
    const int i = idx / N, j = idx - i * N;
    A[i * AP + j] = (double)S[idx];
  } else {
    const int r = idx - N * N;
    if (r < N) A[r * AP + N] = (double)z0[r];
  }
}

// ---------------------------------------------------------------------------
// panel factor (1 block, 512 thr): the ONLY sequential part.
//  - wave 0: 64 rows in registers, 32-step shfl factorization (no barriers)
//  - publishes F11 (L+U mix) + pinv to LDS; U11 -> A for the finish
//  - after 1 barrier: remaining rows do register triangular pass (->Pw),
//    M01 rows [0,k0) right-solve (->Pw), U12 cols forward-solve (->U12,A)
//
// NOTE: every inner triangular loop MUST be fully unrolled so the
// r[]/m[]/u[] register arrays are statically indexed. Without the inner
// pragmas the compiler leaves them runtime-indexed -> scratch (VGPR_Count
// was 68 with 3x 64-VGPR arrays declared!), and the ~500-deep dependent
// chain pays scratch latency per step: 53 us/dispatch, 428 us total.
// __launch_bounds__(512, 2): 8 waves/block = 2 waves/EU is the only
// occupancy this 1-block kernel can have; lets the allocator use 256 VGPRs.
// ---------------------------------------------------------------------------
__global__ __launch_bounds__(512, 2) void panel_factor_kernel(void* __restrict__ wsv,
                                                              int k0) {
  __shared__ double F11[NB][NB + 1];
  __shared__ double pinv[NB];
  double* A    = (double*)((char*)wsv + A_BYTE);
  double* Pw   = (double*)((char*)wsv + PW_BYTE);
  double* U12w = (double*)((char*)wsv + U12_BYTE);
  const int tid   = threadIdx.x;
  const int ct    = k0 + NB;
  const int nrows = N - k0;
  const int tc2   = 258 - ct;          // trailing cols incl rhs
  const bool act  = tid < nrows;
  const int myrow = k0 + tid;

  double r[NB];
  if (act) {
    #pragma unroll
    for (int c = 0; c < NB; ++c) r[c] = A[myrow * AP + k0 + c];
  }

  if (tid < 64) {
    // rows k0..k0+63 (incl all 32 pivots) factored inside one wave via shfl
    #pragma unroll
    for (int j = 0; j < NB; ++j) {
      const double ujj = __shfl(r[j], j);
      const double pj  = 1.0 / ujj;
      const double m   = r[j] * pj;
      #pragma unroll
      for (int j2 = j + 1; j2 < NB; ++j2) {
        const double u = __shfl(r[j2], j);
        if (tid > j && act) r[j2] -= m * u;
      }
      if (tid > j && act) r[j] = m;
    }
    if (tid < NB) {
      #pragma unroll
      for (int c = 0; c < NB; ++c) {
        F11[tid][c] = r[c];
        A[(k0 + tid) * AP + (k0 + c)] = r[c];   // U11 (and L mults) for finish
      }
      pinv[tid] = 1.0 / r[tid];
    } else if (act) {
      #pragma unroll
      for (int c = 0; c < NB; ++c) Pw[c * N + myrow] = r[c];
    }
  }
  __syncthreads();

  if (tid >= 64 && act) {
    // rows k0+64..N: register triangular pass vs U11
    #pragma unroll
    for (int j = 0; j < NB; ++j) {
      const double m = r[j] * pinv[j];
      r[j] = m;
      #pragma unroll
      for (int j2 = j + 1; j2 < NB; ++j2) r[j2] -= m * F11[j][j2];
    }
    #pragma unroll
    for (int c = 0; c < NB; ++c) Pw[c * N + myrow] = r[c];
  } else if (tid >= 256 && tid < 256 + k0) {
    // M01 row r0: right-solve m * U11 = a01
    const int r0 = tid - 256;
    double m[NB];
    #pragma unroll
    for (int j = 0; j < NB; ++j) {
      double vv = A[r0 * AP + (k0 + j)];
      #pragma unroll
      for (int t = 0; t < j; ++t) vv -= m[t] * F11[t][j];
      vv *= pinv[j];
      m[j] = vv;
    }
    #pragma unroll
    for (int j = 0; j < NB; ++j) Pw[j * N + r0] = m[j];
  }

  // U12 forward solve: depends only on F11 (+pristine pivot-row trailing A);
  // runs sequentially within each thread after its role above — no barrier.
  if (tid < tc2) {
    const int c = ct + tid;
    double u[NB];
    #pragma unroll
    for (int jr = 0; jr < NB; ++jr) {
      double vv = A[(k0 + jr) * AP + c];
      #pragma unroll
      for (int t = 0; t < jr; ++t) vv -= F11[jr][t] * u[t];
      u[jr] = vv;
      U12w[jr * 226 + tid] = vv;
      A[(k0 + jr) * AP + c] = vv;   // pivot rows' trailing (incl rhs)
    }
  }
}

// ---------------------------------------------------------------------------
// panel update (grid-parallel Jordan rank-32 GEMM):
//   rows R = [0,k0) U [ct,N)  (225 rows, R-index rb; gr = rb<k0 ? rb : rb+32)
//   cols [ct, 258): A[gr][c] -= sum_t Pw[t][gr] * U12[t][c-ct]
// block tile = 32 rows x 64 cols; thread tile = 2x4.
// ---------------------------------------------------------------------------
__global__ __launch_bounds__(256) void panel_update_kernel(void* __restrict__ wsv,
                                                           int k0, int tc2) {
  __shared__ double Pl[NB][NB + 1];
  __shared__ __align__(16) double Ul[NB][66];
  double* A = (double*)((char*)wsv + A_BYTE);
  const double* Pw   = (const double*)((const char*)wsv + PW_BYTE);
  const double* U12w = (const double*)((const char*)wsv + U12_BYTE);
  const int tid = threadIdx.x;
  const int ct  = k0 + NB;
  const int rb0 = blockIdx.x * 32;
  const int c0  = blockIdx.y * 64;

  for (int i = tid; i < 32 * 32; i += 256) {
    const int t = i >> 5, rr = i & 31;
    const int rb = rb0 + rr;
    const int gr = (rb < k0) ? rb : rb + NB;
    Pl[t][rr] = (rb < 225) ? Pw[t * N + gr] : 0.0;
  }
  for (int i = tid; i < 32 * 64; i += 256) {
    const int t = i >> 6, c = i & 63;
    Ul[t][c] = (c0 + c < tc2) ? U12w[t * 226 + c0 + c] : 0.0;
  }
  __syncthreads();

  const int tr  = tid >> 4;          // 0..15 -> rows tr*2 .. +1
  const int tcx = (tid & 15) * 4;    // cols tcx .. +3
  double acc[2][4];
  #pragma unroll
  for (int rr = 0; rr < 2; ++rr) {
    const int rb = rb0 + tr * 2 + rr;
    const int gr = (rb < k0) ? rb : rb + NB;
    #pragma unroll
    for (int c = 0; c < 4; ++c)
      acc[rr][c] = (rb < 225 && (c0 + tcx + c) < tc2)
                 ? A[gr * AP + ct + c0 + tcx + c] : 0.0;
  }
  #pragma unroll
  for (int t = 0; t < NB; ++t) {
    const double p0 = Pl[t][tr * 2], p1 = Pl[t][tr * 2 + 1];
    const double2 u0 = *(const double2*)&Ul[t][tcx];
    const double2 u1 = *(const double2*)&Ul[t][tcx + 2];
    acc[0][0] -= p0 * u0.x; acc[0][1] -= p0 * u0.y;
    acc[0][2] -= p0 * u1.x; acc[0][3] -= p0 * u1.y;
    acc[1][0] -= p1 * u0.x; acc[1][1] -= p1 * u0.y;
    acc[1][2] -= p1 * u1.x; acc[1][3] -= p1 * u1.y;
  }
  #pragma unroll
  for (int rr = 0; rr < 2; ++rr) {
    const int rb = rb0 + tr * 2 + rr;
    const int gr = (rb < k0) ? rb : rb + NB;
    #pragma unroll
    for (int c = 0; c < 4; ++c)
      if (rb < 225 && (c0 + tcx + c) < tc2)
        A[gr * AP + ct + c0 + tcx + c] = acc[rr][c];
  }
}

// ---------------------------------------------------------------------------
// finish: x256 division, then 8 independent per-panel 32-step back-substs
// ---------------------------------------------------------------------------
__global__ __launch_bounds__(256) void finish_kernel(void* __restrict__ wsv) {
  __shared__ double xs[N];
  __shared__ double rr[256];
  double* A   = (double*)((char*)wsv + A_BYTE);
  float*  w0f = (float*)((char*)wsv + W0_BYTE);
  const int tid = threadIdx.x;
  if (tid == 0) xs[256] = A[256 * AP + 257] / A[256 * AP + 256];
  __syncthreads();
  const double x256 = xs[256];
  rr[tid] = A[tid * AP + 257] - A[tid * AP + 256] * x256;
  __syncthreads();
  const int fk0 = tid & ~31;
  const int fs  = tid & 31;
  for (int j = 31; j >= 0; --j) {
    if (fs == j) xs[fk0 + j] = rr[fk0 + j] / A[(fk0 + j) * AP + (fk0 + j)];
    __syncthreads();
    if (fs < j) rr[fk0 + fs] -= A[(fk0 + fs) * AP + (fk0 + j)] * xs[fk0 + j];
    __syncthreads();
  }
  w0f[tid] = (float)xs[tid];
  if (tid == 0) w0f[256] = (float)xs[256];
}

// ---------------------------------------------------------------------------
// combine: out[(b,l), i] = sum_d S[i,d] * W[(b,l), d]
// ---------------------------------------------------------------------------
#define NL 8
__global__ __launch_bounds__(320) void combine_kernel(const float* __restrict__ S,
                                                      const float* __restrict__ om,
                                                      const void* __restrict__ wsv,
                                                      float* __restrict__ out) {
  const int tid = threadIdx.x;
  const int b  = blockIdx.y;
  const int l0 = blockIdx.x * NL;
  const float* w0  = (const float*)((const char*)wsv + W0_BYTE);
  const float* cxy = (const float*)((const char*)wsv + CXY_BYTE);
  __shared__ float Wl[NL][N];
  __shared__ float omsh[2 * MM];
  __shared__ float cxs[NL], cys[NL];

  for (int idx = tid; idx < 2 * MM; idx += 320) omsh[idx] = om[idx];
  if (tid < NL) {
    cxs[tid] = cxy[((size_t)(b * LL) + l0 + tid) * 2];
    cys[tid] = cxy[((size_t)(b * LL) + l0 + tid) * 2 + 1];
  }
  __syncthreads();

  for (int idx = tid; idx < NL * N; idx += 320) {
    const int r = idx / N;
    const int d = idx - r * N;
    float v;
    if (d == 0) {
      v = w0[0];
    } else {
      const int m = (d - 1) >> 1;
      const int pq = 2 * m + 1;
      const float t = cxs[r] * omsh[2 * m] + cys[r] * omsh[2 * m + 1];
      float s, c;
      sincosf(t, &s, &c);
      const float a0 = w0[pq], a1 = w0[pq + 1];
      v = (d & 1) ? (c * a0 - s * a1) : (s * a0 + c * a1);
    }
    Wl[r][d] = v;
  }
  __syncthreads();

  const int i = tid;
  if (i < N) {
    const float* Si = S + (size_t)i * N;
    float acc[NL];
    #pragma unroll
    for (int r = 0; r < NL; ++r) acc[r] = 0.0f;
    #pragma unroll 4
    for (int d = 0; d < N; ++d) {
      const float sv = Si[d];
      #pragma unroll
      for (int r = 0; r < NL; ++r) acc[r] += sv * Wl[r][d];
    }
    const size_t base = (size_t)(b * LL + l0) * N + i;
    #pragma unroll
    for (int r = 0; r < NL; ++r) out[base + (size_t)r * N] = acc[r];
    if (l0 + NL == LL) {
      out[(size_t)BB * LL * N + (size_t)b * N + i] = acc[NL - 1];
    }
  }
}

extern "C" void kernel_launch(void* const* d_in, const int* in_sizes, int n_in,
                              void* d_out, int out_size, void* d_ws, size_t ws_size,
                              hipStream_t stream) {
  const float* x  = (const float*)d_in[0];   // (B, L, 2)
  const float* z0 = (const float*)d_in[1];   // (D,)
  const float* om = (const float*)d_in[2];   // (M, 2)
  const float* S  = (const float*)d_in[3];   // (D, D)
  float* out = (float*)d_out;                // outputs (B,L,D) then z_final (B,D)

  hipLaunchKernelGGL(scan_kernel,  dim3(1),   dim3(512), 0, stream, x, d_ws);
  hipLaunchKernelGGL(stage_kernel, dim3(260), dim3(256), 0, stream, S, z0, d_ws);
  for (int p = 0; p < 8; ++p) {
    const int k0  = p * NB;
    const int tc2 = 258 - (k0 + NB);
    hipLaunchKernelGGL(panel_factor_kernel, dim3(1), dim3(512), 0, stream, d_ws, k0);
    hipLaunchKernelGGL(panel_update_kernel, dim3(8, (tc2 + 63) / 64), dim3(256),
                       0, stream, d_ws, k0, tc2);
  }
  hipLaunchKernelGGL(finish_kernel, dim3(1), dim3(256), 0, stream, d_ws);
  hipLaunchKernelGGL(combine_kernel, dim3(LL / NL, BB), dim3(320), 0, stream, S, om, d_ws, out);
}